// Round 12
// baseline (591.663 us; speedup 1.0000x reference)
//
#include <hip/hip_runtime.h>
#include <hip/hip_fp16.h>
#include <hip/hip_cooperative_groups.h>

namespace cg = cooperative_groups;

#define N_NODES 50000
#define N_EDGES 625000
#define FEAT 128
#define NEG_SLOPE 0.2f
#define NB_SCAN 196   // ceil(50000/256)
#define CSR_GRID 1024

typedef __attribute__((ext_vector_type(8))) short bf16x8;
typedef __attribute__((ext_vector_type(4))) float f32x4;

__device__ __forceinline__ unsigned short f2bf(float f) {
  unsigned u = __float_as_uint(f);
  u += 0x7fffu + ((u >> 16) & 1u);        // round-to-nearest-even
  return (unsigned short)(u >> 16);
}
__device__ __forceinline__ float bf2f(unsigned short s) {
  return __uint_as_float(((unsigned)s) << 16);
}

// ---------------- fused CSR/prep: 5 dispatches -> 1 cooperative kernel ----------------
// phase0: W split/permute + cnt zero | phase1: hist | phase2: per-block partials
// phase3: merged top+down scan       | phase4: fill. grid.sync() between phases.
// Bodies are byte-equivalent ports of the R11 kernels (grid-stride where needed).

__global__ __launch_bounds__(256) void csr_fused_kernel(
    const float* __restrict__ W0, const float* __restrict__ W1, const float* __restrict__ W2,
    unsigned short* __restrict__ wfhi, unsigned short* __restrict__ wflo,
    int* __restrict__ cnt, const int* __restrict__ dst, const int* __restrict__ src,
    int* __restrict__ part, int* __restrict__ offs, int* __restrict__ ssrc)
{
  cg::grid_group grid = cg::this_grid();
  const int tid = threadIdx.x;
  __shared__ int s[256];
  __shared__ int sl[256];

  // ---- phase 0: prep W + zero cnt (392 vblocks, grid >= 392: direct) ----
  {
    int bb = blockIdx.x;
    if (bb < 192) {
      int idx = bb * 256 + tid;              // 3 * 16384
      if (idx < 3 * FEAT * FEAT) {
        int l = idx >> 14, rem = idx & 16383;
        int e = rem & 7, lane = (rem >> 3) & 63, kb = (rem >> 9) & 3, ct = rem >> 11;
        int col = ct * 16 + (lane & 15);
        int k   = kb * 32 + (lane >> 4) * 8 + e;
        const float* W = (l == 0) ? W0 : ((l == 1) ? W1 : W2);
        float v = W[k * FEAT + col];         // W is [k][col]
        unsigned short hi = f2bf(v);
        wfhi[idx] = hi;
        wflo[idx] = f2bf(v - bf2f(hi));
      }
    } else if (bb < 392) {
      int i = (bb - 192) * 256 + tid;
      if (i < N_NODES + 16) cnt[i] = 0;
    }
  }
  grid.sync();

  // ---- phase 1: histogram of dst ----
  for (int e = blockIdx.x * 256 + tid; e < N_EDGES; e += CSR_GRID * 256)
    atomicAdd(&cnt[dst[e]], 1);
  grid.sync();

  // ---- phase 2: per-block partial sums (196 vblocks) ----
  if (blockIdx.x < NB_SCAN) {
    int i = blockIdx.x * 256 + tid;
    s[tid] = (i < N_NODES) ? cnt[i] : 0;
    __syncthreads();
    for (int o = 128; o > 0; o >>= 1) {
      if (tid < o) s[tid] += s[tid + o];
      __syncthreads();
    }
    if (tid == 0) part[blockIdx.x] = s[0];
  }
  grid.sync();

  // ---- phase 3: merged top+down scan (196 vblocks) ----
  if (blockIdx.x < NB_SCAN) {
    int pv = (tid < NB_SCAN) ? part[tid] : 0;
    s[tid] = pv;
    __syncthreads();
    for (int o = 1; o < 256; o <<= 1) {
      int t = (tid >= o) ? s[tid - o] : 0;
      __syncthreads();
      s[tid] += t;
      __syncthreads();
    }
    const int blockPrefix = (blockIdx.x == 0) ? 0 : s[blockIdx.x - 1];
    if (blockIdx.x == 0 && tid == 0) offs[N_NODES] = s[NB_SCAN - 1];

    int i = blockIdx.x * 256 + tid;
    int v = (i < N_NODES) ? cnt[i] : 0;
    sl[tid] = v;
    __syncthreads();
    for (int o = 1; o < 256; o <<= 1) {
      int t = (tid >= o) ? sl[tid - o] : 0;
      __syncthreads();
      sl[tid] += t;
      __syncthreads();
    }
    if (i < N_NODES) {
      int excl = sl[tid] - v + blockPrefix;
      offs[i] = excl;
      cnt[i] = excl;  // becomes the fill cursor
    }
  }
  grid.sync();

  // ---- phase 4: fill ssrc (sorted-by-dst sources) ----
  for (int e = blockIdx.x * 256 + tid; e < N_EDGES; e += CSR_GRID * 256) {
    int pos = atomicAdd(&cnt[dst[e]], 1);
    ssrc[pos] = src[e];
  }
}

// ---------------- GEMM via split-bf16 MFMA, W staged in LDS (R11, frozen) ----------------

__global__ __launch_bounds__(256) void gemm_mfma_kernel(
    const float* __restrict__ inF, const __half* __restrict__ inH,
    const unsigned short* __restrict__ wfhi, const unsigned short* __restrict__ wflo,
    const float* __restrict__ al, const float* __restrict__ ar,
    __half* __restrict__ h, float* __restrict__ el, float* __restrict__ er,
    int fp16relu_in)
{
  __shared__ __align__(16) char smem[32768];   // union: wl 32KB | tile[64][132] 16.9KB
  unsigned short* wl = (unsigned short*)smem;
  typedef __half (*tile_t)[132];
  tile_t tile = (tile_t)smem;

  const int tid = threadIdx.x;
  const int wave = tid >> 6, lane = tid & 63;
  const int lrow = lane & 15, lkb = lane >> 4;
  const int arow_i = blockIdx.x * 64 + wave * 16 + lrow;
  const bool avalid = arow_i < N_NODES;

  // ---- issue stage of kb-pair 0 (overlaps with A-load below) ----
#pragma unroll
  for (int q = 0; q < 8; ++q) {
    int idx = q * 256 + tid;
    int hilo = idx >> 10, r = idx & 1023, frag = r >> 6, word = r & 63;
    int ct = frag >> 1, kb = frag & 1;                 // p=0: kb in {0,1}
    const uint4* s4 = (const uint4*)(hilo ? wflo : wfhi);
    uint4 v = s4[(ct * 4 + kb) * 64 + word];
    *(uint4*)&wl[((hilo * 16 + frag) << 9) + word * 8] = v;
  }

  // ---- A row fragments: 4 k-blocks x 8 elems, split to bf16 hi/lo ----
  bf16x8 ahi[4], alo[4];
#pragma unroll
  for (int kb = 0; kb < 4; ++kb) {
    float a[8];
    if (avalid) {
      if (fp16relu_in) {
        const unsigned short* aH = (const unsigned short*)inH + (size_t)arow_i * FEAT;
        uint4 rv = *(const uint4*)(aH + kb * 32 + lkb * 8);
        const __half2* hp = (const __half2*)&rv;
#pragma unroll
        for (int e2 = 0; e2 < 4; ++e2) {
          float2 f = __half22float2(hp[e2]);
          a[e2 * 2] = fmaxf(f.x, 0.f); a[e2 * 2 + 1] = fmaxf(f.y, 0.f);
        }
      } else {
        const float* arow = inF + (size_t)arow_i * FEAT;
        float4 v0 = *(const float4*)(arow + kb * 32 + lkb * 8);
        float4 v1 = *(const float4*)(arow + kb * 32 + lkb * 8 + 4);
        a[0] = v0.x; a[1] = v0.y; a[2] = v0.z; a[3] = v0.w;
        a[4] = v1.x; a[5] = v1.y; a[6] = v1.z; a[7] = v1.w;
      }
    } else {
#pragma unroll
      for (int e = 0; e < 8; ++e) a[e] = 0.f;
    }
#pragma unroll
    for (int e = 0; e < 8; ++e) {
      unsigned short hb = f2bf(a[e]);
      ahi[kb][e] = (short)hb;
      alo[kb][e] = (short)f2bf(a[e] - bf2f(hb));
    }
  }

  f32x4 acc[8];
#pragma unroll
  for (int ct = 0; ct < 8; ++ct)
#pragma unroll
    for (int r = 0; r < 4; ++r) acc[ct][r] = 0.f;

  // ---- half 0: kb 0,1 ----
  __syncthreads();
#pragma unroll
  for (int ct = 0; ct < 8; ++ct) {
#pragma unroll
    for (int kb1 = 0; kb1 < 2; ++kb1) {
      bf16x8 bhi = *(const bf16x8*)&wl[((ct * 2 + kb1) << 9) + lane * 8];
      bf16x8 blo = *(const bf16x8*)&wl[((16 + ct * 2 + kb1) << 9) + lane * 8];
      acc[ct] = __builtin_amdgcn_mfma_f32_16x16x32_bf16(ahi[kb1], bhi, acc[ct], 0, 0, 0);
      acc[ct] = __builtin_amdgcn_mfma_f32_16x16x32_bf16(ahi[kb1], blo, acc[ct], 0, 0, 0);
      acc[ct] = __builtin_amdgcn_mfma_f32_16x16x32_bf16(alo[kb1], bhi, acc[ct], 0, 0, 0);
    }
  }
  __syncthreads();

  // ---- stage + compute half 1: kb 2,3 ----
#pragma unroll
  for (int q = 0; q < 8; ++q) {
    int idx = q * 256 + tid;
    int hilo = idx >> 10, r = idx & 1023, frag = r >> 6, word = r & 63;
    int ct = frag >> 1, kb = 2 + (frag & 1);
    const uint4* s4 = (const uint4*)(hilo ? wflo : wfhi);
    uint4 v = s4[(ct * 4 + kb) * 64 + word];
    *(uint4*)&wl[((hilo * 16 + frag) << 9) + word * 8] = v;
  }
  __syncthreads();
#pragma unroll
  for (int ct = 0; ct < 8; ++ct) {
#pragma unroll
    for (int kb1 = 0; kb1 < 2; ++kb1) {
      bf16x8 bhi = *(const bf16x8*)&wl[((ct * 2 + kb1) << 9) + lane * 8];
      bf16x8 blo = *(const bf16x8*)&wl[((16 + ct * 2 + kb1) << 9) + lane * 8];
      acc[ct] = __builtin_amdgcn_mfma_f32_16x16x32_bf16(ahi[2 + kb1], bhi, acc[ct], 0, 0, 0);
      acc[ct] = __builtin_amdgcn_mfma_f32_16x16x32_bf16(ahi[2 + kb1], blo, acc[ct], 0, 0, 0);
      acc[ct] = __builtin_amdgcn_mfma_f32_16x16x32_bf16(alo[2 + kb1], bhi, acc[ct], 0, 0, 0);
    }
  }
  __syncthreads();   // wl's last read above; tile (same memory) written below

  // ---- epilogue: el/er via shfl reduce; h via LDS tile -> coalesced fp16 stores ----
  float alv[8], arv[8];
#pragma unroll
  for (int ct = 0; ct < 8; ++ct) { alv[ct] = al[ct * 16 + lrow]; arv[ct] = ar[ct * 16 + lrow]; }

  const int lrow0 = wave * 16 + lkb * 4;
#pragma unroll
  for (int r = 0; r < 4; ++r) {
    float pel = 0.f, per_ = 0.f;
#pragma unroll
    for (int ct = 0; ct < 8; ++ct) {
      float v = acc[ct][r];
      tile[lrow0 + r][ct * 16 + lrow] = __float2half_rn(v);
      pel  = fmaf(v, alv[ct], pel);
      per_ = fmaf(v, arv[ct], per_);
    }
#pragma unroll
    for (int mask = 8; mask >= 1; mask >>= 1) {
      pel  += __shfl_xor(pel, mask);
      per_ += __shfl_xor(per_, mask);
    }
    int grow = blockIdx.x * 64 + lrow0 + r;
    if (grow < N_NODES && lrow == 0) { el[grow] = pel; er[grow] = per_; }
  }
  __syncthreads();

  const int row0g = blockIdx.x * 64;
#pragma unroll
  for (int it = 0; it < 4; ++it) {
    int idx = it * 256 + tid;
    int row = idx >> 4, c16 = idx & 15;
    int grow = row0g + row;
    if (grow < N_NODES) {
      uint4 v = *(const uint4*)&tile[row][c16 * 8];
      *((uint4*)(h + (size_t)grow * FEAT) + c16) = v;
    }
  }
}

// ---------------- edge softmax + aggregate (R10, frozen): 4 nodes/wave, no max-shift ----

__global__ __launch_bounds__(256) void agg_kernel(
    const __half* __restrict__ h, const float* __restrict__ el,
    const float* __restrict__ er, const int* __restrict__ offs,
    const int* __restrict__ ssrc, const float* __restrict__ bias,
    float* __restrict__ out32, __half* __restrict__ out16, int use16)
{
  const int tid = threadIdx.x;
  const int lane = tid & 63;
  const int qg = lane >> 4, ql = lane & 15;
  const int waveg = (blockIdx.x * 256 + tid) >> 6;
  const int node = waveg * 4 + qg;           // quarter-uniform
  if (node >= N_NODES) return;               // whole quarter exits together

  const int beg = offs[node], end = offs[node + 1];
  const float erd = er[node];
  const unsigned short* __restrict__ hu = (const unsigned short*)h;
  const int qbase = qg * 16;

  float acc[8];
#pragma unroll
  for (int f = 0; f < 8; ++f) acc[f] = 0.f;
  float ds = 0.f;

  for (int base = beg; base < end; base += 16) {
    const int idx = base + ql;
    const bool v = idx < end;
    int s = 0;
    float ex = 0.f;
    if (v) s = ssrc[idx];
    if (v) {
      float t = el[s] + erd;
      t = t > 0.f ? t : NEG_SLOPE * t;
      ex = __expf(t);
    }
    ds += ex;

    const int ne = min(16, end - base);
    for (int j = 0; j < ne; j += 4) {
      // 4 edges in flight; slots >= ne have s=0 (hot row 0), ex=0 (contribute nothing)
      int   s0 = __shfl(s,  qbase + j),     s1 = __shfl(s,  qbase + j + 1);
      int   s2 = __shfl(s,  qbase + j + 2), s3 = __shfl(s,  qbase + j + 3);
      float w0 = __shfl(ex, qbase + j),     w1 = __shfl(ex, qbase + j + 1);
      float w2 = __shfl(ex, qbase + j + 2), w3 = __shfl(ex, qbase + j + 3);
      uint4 r0 = *(const uint4*)(hu + (((size_t)s0) << 7) + (ql << 3));
      uint4 r1 = *(const uint4*)(hu + (((size_t)s1) << 7) + (ql << 3));
      uint4 r2 = *(const uint4*)(hu + (((size_t)s2) << 7) + (ql << 3));
      uint4 r3 = *(const uint4*)(hu + (((size_t)s3) << 7) + (ql << 3));
#pragma unroll
      for (int l = 0; l < 4; ++l) {
        const uint4& rr = (l == 0) ? r0 : (l == 1) ? r1 : (l == 2) ? r2 : r3;
        const float  ww = (l == 0) ? w0 : (l == 1) ? w1 : (l == 2) ? w2 : w3;
        float2 f0 = __half22float2(__builtin_bit_cast(__half2, rr.x));
        float2 f1 = __half22float2(__builtin_bit_cast(__half2, rr.y));
        float2 f2 = __half22float2(__builtin_bit_cast(__half2, rr.z));
        float2 f3 = __half22float2(__builtin_bit_cast(__half2, rr.w));
        acc[0] = fmaf(ww, f0.x, acc[0]); acc[1] = fmaf(ww, f0.y, acc[1]);
        acc[2] = fmaf(ww, f1.x, acc[2]); acc[3] = fmaf(ww, f1.y, acc[3]);
        acc[4] = fmaf(ww, f2.x, acc[4]); acc[5] = fmaf(ww, f2.y, acc[5]);
        acc[6] = fmaf(ww, f3.x, acc[6]); acc[7] = fmaf(ww, f3.y, acc[7]);
      }
    }
  }

  // fold denom within the 16-lane quarter (masks < 16 stay in-group)
#pragma unroll
  for (int mask = 8; mask >= 1; mask >>= 1) ds += __shfl_xor(ds, mask);
  const float inv = ds > 0.f ? 1.f / ds : 0.f;   // deg==0 -> out = bias

  float4 b0 = ((const float4*)bias)[ql * 2];
  float4 b1 = ((const float4*)bias)[ql * 2 + 1];
  float o0 = fmaf(acc[0], inv, b0.x), o1 = fmaf(acc[1], inv, b0.y);
  float o2 = fmaf(acc[2], inv, b0.z), o3 = fmaf(acc[3], inv, b0.w);
  float o4 = fmaf(acc[4], inv, b1.x), o5 = fmaf(acc[5], inv, b1.y);
  float o6 = fmaf(acc[6], inv, b1.z), o7 = fmaf(acc[7], inv, b1.w);

  if (use16) {
    __half2 o[4];
    o[0] = __floats2half2_rn(o0, o1);
    o[1] = __floats2half2_rn(o2, o3);
    o[2] = __floats2half2_rn(o4, o5);
    o[3] = __floats2half2_rn(o6, o7);
    ((uint4*)(out16 + ((size_t)node << 7)))[ql] = *(const uint4*)o;
  } else {
    float4* op = (float4*)(out32 + ((size_t)node << 7)) + ql * 2;
    op[0] = make_float4(o0, o1, o2, o3);
    op[1] = make_float4(o4, o5, o6, o7);
  }
}

// ---------------- launch ----------------

extern "C" void kernel_launch(void* const* d_in, const int* in_sizes, int n_in,
                              void* d_out, int out_size, void* d_ws, size_t ws_size,
                              hipStream_t stream) {
  const float* x  = (const float*)d_in[0];
  const int* src  = (const int*)d_in[1];
  const int* dst  = (const int*)d_in[2];
  const float* W[3]  = {(const float*)d_in[3],  (const float*)d_in[7],  (const float*)d_in[11]};
  const float* al[3] = {(const float*)d_in[4],  (const float*)d_in[8],  (const float*)d_in[12]};
  const float* ar[3] = {(const float*)d_in[5],  (const float*)d_in[9],  (const float*)d_in[13]};
  const float* b[3]  = {(const float*)d_in[6],  (const float*)d_in[10], (const float*)d_in[14]};

  // workspace layout (~29 MB)
  __half* hH    = (__half*)d_ws;                      // 6,400,000 half : current layer h
  __half* out16 = hH + 6400000;                       // 6,400,000 half : inter-layer buffer
  float*  el    = (float*)(out16 + 6400000);          // 50,016 f
  float*  er    = el + 50016;                         // 50,016 f
  int*    cnt   = (int*)(er + 50016);                 // 50,016 i
  int*    offs  = cnt + 50016;                        // 50,016 i
  int*    part  = offs + 50016;                       // 256 i
  int*    ssrc  = part + 256;                         // 625,000 i
  unsigned short* wfhi = (unsigned short*)(ssrc + 625000);  // 3*16384 bf16 (fragment-major)
  unsigned short* wflo = wfhi + 3 * FEAT * FEAT;            // 3*16384 bf16

  // ---- fused prep + CSR build: ONE cooperative dispatch (was 5) ----
  {
    const float* W0 = W[0]; const float* W1 = W[1]; const float* W2 = W[2];
    void* args[] = {(void*)&W0, (void*)&W1, (void*)&W2,
                    (void*)&wfhi, (void*)&wflo, (void*)&cnt,
                    (void*)&dst, (void*)&src, (void*)&part,
                    (void*)&offs, (void*)&ssrc};
    hipLaunchCooperativeKernel((void*)csr_fused_kernel, dim3(CSR_GRID), dim3(256),
                               args, 0, stream);
  }

  const int gemm_grid = (N_NODES + 63) / 64;       // 782 blocks, 64 rows each
  const int agg_grid  = (N_NODES + 15) / 16;       // 3125 blocks: 4 waves x 4 nodes each
  float* outf = (float*)d_out;

  for (int l = 0; l < 3; ++l) {
    gemm_mfma_kernel<<<gemm_grid, 256, 0, stream>>>(
        (l == 0) ? x : nullptr, (l == 0) ? nullptr : out16,
        wfhi + l * FEAT * FEAT, wflo + l * FEAT * FEAT,
        al[l], ar[l], hH, el, er, l > 0 ? 1 : 0);
    agg_kernel<<<agg_grid, 256, 0, stream>>>(
        hH, el, er, offs, ssrc, b[l], outf, out16, l < 2 ? 1 : 0);
  }
}

// Round 13
// 209.809 us; speedup vs baseline: 2.8200x; 2.8200x over previous
//
#include <hip/hip_runtime.h>
#include <hip/hip_fp16.h>

#define N_NODES 50000
#define N_EDGES 625000
#define FEAT 128
#define NEG_SLOPE 0.2f
#define NB_SCAN 196   // ceil(50000/256)

typedef __attribute__((ext_vector_type(8))) short bf16x8;
typedef __attribute__((ext_vector_type(4))) float f32x4;

__device__ __forceinline__ unsigned short f2bf(float f) {
  unsigned u = __float_as_uint(f);
  u += 0x7fffu + ((u >> 16) & 1u);        // round-to-nearest-even
  return (unsigned short)(u >> 16);
}
__device__ __forceinline__ float bf2f(unsigned short s) {
  return __uint_as_float(((unsigned)s) << 16);
}

// ---------------- prep (W split/permute) + cnt zero, one dispatch ----------------
// wf[layer][ct][kb][lane][e]: each (ct,kb) B-fragment is one coalesced 1KB wave load.
// B layout for mfma_16x16x32_bf16: col = lane&15, k = kb*32 + (lane>>4)*8 + e.

__global__ __launch_bounds__(256) void prepzero_kernel(
    const float* __restrict__ W0, const float* __restrict__ W1, const float* __restrict__ W2,
    unsigned short* __restrict__ wfhi, unsigned short* __restrict__ wflo,
    int* __restrict__ cnt) {
  int bb = blockIdx.x;
  if (bb < 192) {
    int idx = bb * 256 + threadIdx.x;        // 3 * 16384
    if (idx >= 3 * FEAT * FEAT) return;
    int l = idx >> 14, rem = idx & 16383;
    int e = rem & 7, lane = (rem >> 3) & 63, kb = (rem >> 9) & 3, ct = rem >> 11;
    int col = ct * 16 + (lane & 15);
    int k   = kb * 32 + (lane >> 4) * 8 + e;
    const float* W = (l == 0) ? W0 : ((l == 1) ? W1 : W2);
    float v = W[k * FEAT + col];             // W is [k][col]
    unsigned short hi = f2bf(v);
    wfhi[idx] = hi;
    wflo[idx] = f2bf(v - bf2f(hi));
  } else {
    int i = (bb - 192) * 256 + threadIdx.x;
    if (i < N_NODES + 16) cnt[i] = 0;
  }
}

// ---------------- CSR build ----------------

__global__ __launch_bounds__(256) void hist_kernel(const int* __restrict__ dst,
                                                   int* __restrict__ cnt) {
  int e = blockIdx.x * 256 + threadIdx.x;
  if (e < N_EDGES) atomicAdd(&cnt[dst[e]], 1);
}

__global__ __launch_bounds__(256) void scan_part_kernel(const int* __restrict__ cnt,
                                                        int* __restrict__ part) {
  __shared__ int s[256];
  int i = blockIdx.x * 256 + threadIdx.x;
  s[threadIdx.x] = (i < N_NODES) ? cnt[i] : 0;
  __syncthreads();
  for (int o = 128; o > 0; o >>= 1) {
    if (threadIdx.x < o) s[threadIdx.x] += s[threadIdx.x + o];
    __syncthreads();
  }
  if (threadIdx.x == 0) part[blockIdx.x] = s[0];
}

__global__ __launch_bounds__(256) void scan_top_kernel(int* __restrict__ part,
                                                       int* __restrict__ offs) {
  __shared__ int s[256];
  int tid = threadIdx.x;
  int v = (tid < NB_SCAN) ? part[tid] : 0;
  s[tid] = v;
  __syncthreads();
  for (int o = 1; o < 256; o <<= 1) {
    int t = (tid >= o) ? s[tid - o] : 0;
    __syncthreads();
    s[tid] += t;
    __syncthreads();
  }
  if (tid < NB_SCAN) part[tid] = s[tid] - v;  // exclusive scan of block sums
  if (tid == 255) offs[N_NODES] = s[255];     // total (= N_EDGES)
}

__global__ __launch_bounds__(256) void scan_down_kernel(int* __restrict__ cnt,
                                                        const int* __restrict__ part,
                                                        int* __restrict__ offs) {
  __shared__ int s[256];
  int tid = threadIdx.x;
  int i = blockIdx.x * 256 + tid;
  int v = (i < N_NODES) ? cnt[i] : 0;
  s[tid] = v;
  __syncthreads();
  for (int o = 1; o < 256; o <<= 1) {
    int t = (tid >= o) ? s[tid - o] : 0;
    __syncthreads();
    s[tid] += t;
    __syncthreads();
  }
  if (i < N_NODES) {
    int excl = s[tid] - v + part[blockIdx.x];
    offs[i] = excl;
    cnt[i] = excl;  // becomes the fill cursor
  }
}

__global__ __launch_bounds__(256) void fill_kernel(const int* __restrict__ src,
                                                   const int* __restrict__ dst,
                                                   int* __restrict__ cursor,
                                                   int* __restrict__ ssrc) {
  int e = blockIdx.x * 256 + threadIdx.x;
  if (e < N_EDGES) {
    int pos = atomicAdd(&cursor[dst[e]], 1);
    ssrc[pos] = src[e];
  }
}

// ---------------- GEMM via split-bf16 MFMA, W staged in LDS (R9/R10 exact) ----------------

__global__ __launch_bounds__(256) void gemm_mfma_kernel(
    const float* __restrict__ inF, const __half* __restrict__ inH,
    const unsigned short* __restrict__ wfhi, const unsigned short* __restrict__ wflo,
    const float* __restrict__ al, const float* __restrict__ ar,
    __half* __restrict__ h, float* __restrict__ el, float* __restrict__ er,
    int fp16relu_in)
{
  __shared__ unsigned short wl[16384];   // 32 KB: one kb-pair of W hi+lo fragments
  __shared__ __half tile[64][132];       // 16.9 KB h-transpose tile
  const int tid = threadIdx.x;
  const int wave = tid >> 6, lane = tid & 63;
  const int lrow = lane & 15, lkb = lane >> 4;
  const int arow_i = blockIdx.x * 64 + wave * 16 + lrow;
  const bool avalid = arow_i < N_NODES;

  // ---- issue stage of kb-pair 0 (overlaps with A-load below) ----
#pragma unroll
  for (int q = 0; q < 8; ++q) {
    int idx = q * 256 + tid;
    int hilo = idx >> 10, r = idx & 1023, frag = r >> 6, word = r & 63;
    int ct = frag >> 1, kb = frag & 1;                 // p=0: kb in {0,1}
    const uint4* s4 = (const uint4*)(hilo ? wflo : wfhi);
    uint4 v = s4[(ct * 4 + kb) * 64 + word];
    *(uint4*)&wl[((hilo * 16 + frag) << 9) + word * 8] = v;
  }

  // ---- A row fragments: 4 k-blocks x 8 elems, split to bf16 hi/lo ----
  bf16x8 ahi[4], alo[4];
#pragma unroll
  for (int kb = 0; kb < 4; ++kb) {
    float a[8];
    if (avalid) {
      if (fp16relu_in) {
        const unsigned short* aH = (const unsigned short*)inH + (size_t)arow_i * FEAT;
        uint4 rv = *(const uint4*)(aH + kb * 32 + lkb * 8);
        const __half2* hp = (const __half2*)&rv;
#pragma unroll
        for (int e2 = 0; e2 < 4; ++e2) {
          float2 f = __half22float2(hp[e2]);
          a[e2 * 2] = fmaxf(f.x, 0.f); a[e2 * 2 + 1] = fmaxf(f.y, 0.f);
        }
      } else {
        const float* arow = inF + (size_t)arow_i * FEAT;
        float4 v0 = *(const float4*)(arow + kb * 32 + lkb * 8);
        float4 v1 = *(const float4*)(arow + kb * 32 + lkb * 8 + 4);
        a[0] = v0.x; a[1] = v0.y; a[2] = v0.z; a[3] = v0.w;
        a[4] = v1.x; a[5] = v1.y; a[6] = v1.z; a[7] = v1.w;
      }
    } else {
#pragma unroll
      for (int e = 0; e < 8; ++e) a[e] = 0.f;
    }
#pragma unroll
    for (int e = 0; e < 8; ++e) {
      unsigned short hb = f2bf(a[e]);
      ahi[kb][e] = (short)hb;
      alo[kb][e] = (short)f2bf(a[e] - bf2f(hb));
    }
  }

  f32x4 acc[8];
#pragma unroll
  for (int ct = 0; ct < 8; ++ct)
#pragma unroll
    for (int r = 0; r < 4; ++r) acc[ct][r] = 0.f;

  // ---- half 0: kb 0,1 ----
  __syncthreads();
#pragma unroll
  for (int ct = 0; ct < 8; ++ct) {
#pragma unroll
    for (int kb1 = 0; kb1 < 2; ++kb1) {
      bf16x8 bhi = *(const bf16x8*)&wl[((ct * 2 + kb1) << 9) + lane * 8];
      bf16x8 blo = *(const bf16x8*)&wl[((16 + ct * 2 + kb1) << 9) + lane * 8];
      acc[ct] = __builtin_amdgcn_mfma_f32_16x16x32_bf16(ahi[kb1], bhi, acc[ct], 0, 0, 0);
      acc[ct] = __builtin_amdgcn_mfma_f32_16x16x32_bf16(ahi[kb1], blo, acc[ct], 0, 0, 0);
      acc[ct] = __builtin_amdgcn_mfma_f32_16x16x32_bf16(alo[kb1], bhi, acc[ct], 0, 0, 0);
    }
  }
  __syncthreads();

  // ---- stage + compute half 1: kb 2,3 ----
#pragma unroll
  for (int q = 0; q < 8; ++q) {
    int idx = q * 256 + tid;
    int hilo = idx >> 10, r = idx & 1023, frag = r >> 6, word = r & 63;
    int ct = frag >> 1, kb = 2 + (frag & 1);
    const uint4* s4 = (const uint4*)(hilo ? wflo : wfhi);
    uint4 v = s4[(ct * 4 + kb) * 64 + word];
    *(uint4*)&wl[((hilo * 16 + frag) << 9) + word * 8] = v;
  }
  __syncthreads();
#pragma unroll
  for (int ct = 0; ct < 8; ++ct) {
#pragma unroll
    for (int kb1 = 0; kb1 < 2; ++kb1) {
      bf16x8 bhi = *(const bf16x8*)&wl[((ct * 2 + kb1) << 9) + lane * 8];
      bf16x8 blo = *(const bf16x8*)&wl[((16 + ct * 2 + kb1) << 9) + lane * 8];
      acc[ct] = __builtin_amdgcn_mfma_f32_16x16x32_bf16(ahi[2 + kb1], bhi, acc[ct], 0, 0, 0);
      acc[ct] = __builtin_amdgcn_mfma_f32_16x16x32_bf16(ahi[2 + kb1], blo, acc[ct], 0, 0, 0);
      acc[ct] = __builtin_amdgcn_mfma_f32_16x16x32_bf16(alo[2 + kb1], bhi, acc[ct], 0, 0, 0);
    }
  }

  // ---- epilogue: el/er via shfl reduce; h via LDS tile -> coalesced fp16 stores ----
  float alv[8], arv[8];
#pragma unroll
  for (int ct = 0; ct < 8; ++ct) { alv[ct] = al[ct * 16 + lrow]; arv[ct] = ar[ct * 16 + lrow]; }

  const int lrow0 = wave * 16 + lkb * 4;
#pragma unroll
  for (int r = 0; r < 4; ++r) {
    float pel = 0.f, per_ = 0.f;
#pragma unroll
    for (int ct = 0; ct < 8; ++ct) {
      float v = acc[ct][r];
      tile[lrow0 + r][ct * 16 + lrow] = __float2half_rn(v);
      pel  = fmaf(v, alv[ct], pel);
      per_ = fmaf(v, arv[ct], per_);
    }
#pragma unroll
    for (int mask = 8; mask >= 1; mask >>= 1) {
      pel  += __shfl_xor(pel, mask);
      per_ += __shfl_xor(per_, mask);
    }
    int grow = blockIdx.x * 64 + lrow0 + r;
    if (grow < N_NODES && lrow == 0) { el[grow] = pel; er[grow] = per_; }
  }
  __syncthreads();

  const int row0g = blockIdx.x * 64;
#pragma unroll
  for (int it = 0; it < 4; ++it) {
    int idx = it * 256 + tid;
    int row = idx >> 4, c16 = idx & 15;
    int grow = row0g + row;
    if (grow < N_NODES) {
      uint4 v = *(const uint4*)&tile[row][c16 * 8];
      *((uint4*)(h + (size_t)grow * FEAT) + c16) = v;
    }
  }
}

// ---------------- edge softmax + aggregate (R10 exact): 4 nodes/wave, no max-shift ----

__global__ __launch_bounds__(256) void agg_kernel(
    const __half* __restrict__ h, const float* __restrict__ el,
    const float* __restrict__ er, const int* __restrict__ offs,
    const int* __restrict__ ssrc, const float* __restrict__ bias,
    float* __restrict__ out32, __half* __restrict__ out16, int use16)
{
  const int tid = threadIdx.x;
  const int lane = tid & 63;
  const int qg = lane >> 4, ql = lane & 15;
  const int waveg = (blockIdx.x * 256 + tid) >> 6;
  const int node = waveg * 4 + qg;           // quarter-uniform
  if (node >= N_NODES) return;               // whole quarter exits together

  const int beg = offs[node], end = offs[node + 1];
  const float erd = er[node];
  const unsigned short* __restrict__ hu = (const unsigned short*)h;
  const int qbase = qg * 16;

  float acc[8];
#pragma unroll
  for (int f = 0; f < 8; ++f) acc[f] = 0.f;
  float ds = 0.f;

  for (int base = beg; base < end; base += 16) {
    const int idx = base + ql;
    const bool v = idx < end;
    int s = 0;
    float ex = 0.f;
    if (v) s = ssrc[idx];
    if (v) {
      float t = el[s] + erd;
      t = t > 0.f ? t : NEG_SLOPE * t;
      ex = __expf(t);
    }
    ds += ex;

    const int ne = min(16, end - base);
    for (int j = 0; j < ne; j += 4) {
      // 4 edges in flight; slots >= ne have s=0 (hot row 0), ex=0 (contribute nothing)
      int   s0 = __shfl(s,  qbase + j),     s1 = __shfl(s,  qbase + j + 1);
      int   s2 = __shfl(s,  qbase + j + 2), s3 = __shfl(s,  qbase + j + 3);
      float w0 = __shfl(ex, qbase + j),     w1 = __shfl(ex, qbase + j + 1);
      float w2 = __shfl(ex, qbase + j + 2), w3 = __shfl(ex, qbase + j + 3);
      uint4 r0 = *(const uint4*)(hu + (((size_t)s0) << 7) + (ql << 3));
      uint4 r1 = *(const uint4*)(hu + (((size_t)s1) << 7) + (ql << 3));
      uint4 r2 = *(const uint4*)(hu + (((size_t)s2) << 7) + (ql << 3));
      uint4 r3 = *(const uint4*)(hu + (((size_t)s3) << 7) + (ql << 3));
#pragma unroll
      for (int l = 0; l < 4; ++l) {
        const uint4& rr = (l == 0) ? r0 : (l == 1) ? r1 : (l == 2) ? r2 : r3;
        const float  ww = (l == 0) ? w0 : (l == 1) ? w1 : (l == 2) ? w2 : w3;
        float2 f0 = __half22float2(__builtin_bit_cast(__half2, rr.x));
        float2 f1 = __half22float2(__builtin_bit_cast(__half2, rr.y));
        float2 f2 = __half22float2(__builtin_bit_cast(__half2, rr.z));
        float2 f3 = __half22float2(__builtin_bit_cast(__half2, rr.w));
        acc[0] = fmaf(ww, f0.x, acc[0]); acc[1] = fmaf(ww, f0.y, acc[1]);
        acc[2] = fmaf(ww, f1.x, acc[2]); acc[3] = fmaf(ww, f1.y, acc[3]);
        acc[4] = fmaf(ww, f2.x, acc[4]); acc[5] = fmaf(ww, f2.y, acc[5]);
        acc[6] = fmaf(ww, f3.x, acc[6]); acc[7] = fmaf(ww, f3.y, acc[7]);
      }
    }
  }

  // fold denom within the 16-lane quarter (masks < 16 stay in-group)
#pragma unroll
  for (int mask = 8; mask >= 1; mask >>= 1) ds += __shfl_xor(ds, mask);
  const float inv = ds > 0.f ? 1.f / ds : 0.f;   // deg==0 -> out = bias

  float4 b0 = ((const float4*)bias)[ql * 2];
  float4 b1 = ((const float4*)bias)[ql * 2 + 1];
  float o0 = fmaf(acc[0], inv, b0.x), o1 = fmaf(acc[1], inv, b0.y);
  float o2 = fmaf(acc[2], inv, b0.z), o3 = fmaf(acc[3], inv, b0.w);
  float o4 = fmaf(acc[4], inv, b1.x), o5 = fmaf(acc[5], inv, b1.y);
  float o6 = fmaf(acc[6], inv, b1.z), o7 = fmaf(acc[7], inv, b1.w);

  if (use16) {
    __half2 o[4];
    o[0] = __floats2half2_rn(o0, o1);
    o[1] = __floats2half2_rn(o2, o3);
    o[2] = __floats2half2_rn(o4, o5);
    o[3] = __floats2half2_rn(o6, o7);
    ((uint4*)(out16 + ((size_t)node << 7)))[ql] = *(const uint4*)o;
  } else {
    float4* op = (float4*)(out32 + ((size_t)node << 7)) + ql * 2;
    op[0] = make_float4(o0, o1, o2, o3);
    op[1] = make_float4(o4, o5, o6, o7);
  }
}

// ---------------- launch ----------------

extern "C" void kernel_launch(void* const* d_in, const int* in_sizes, int n_in,
                              void* d_out, int out_size, void* d_ws, size_t ws_size,
                              hipStream_t stream) {
  const float* x  = (const float*)d_in[0];
  const int* src  = (const int*)d_in[1];
  const int* dst  = (const int*)d_in[2];
  const float* W[3]  = {(const float*)d_in[3],  (const float*)d_in[7],  (const float*)d_in[11]};
  const float* al[3] = {(const float*)d_in[4],  (const float*)d_in[8],  (const float*)d_in[12]};
  const float* ar[3] = {(const float*)d_in[5],  (const float*)d_in[9],  (const float*)d_in[13]};
  const float* b[3]  = {(const float*)d_in[6],  (const float*)d_in[10], (const float*)d_in[14]};

  // workspace layout (~29 MB)
  __half* hH    = (__half*)d_ws;                      // 6,400,000 half : current layer h
  __half* out16 = hH + 6400000;                       // 6,400,000 half : inter-layer buffer
  float*  el    = (float*)(out16 + 6400000);          // 50,016 f
  float*  er    = el + 50016;                         // 50,016 f
  int*    cnt   = (int*)(er + 50016);                 // 50,016 i
  int*    offs  = cnt + 50016;                        // 50,016 i
  int*    part  = offs + 50016;                       // 256 i
  int*    ssrc  = part + 256;                         // 625,000 i
  unsigned short* wfhi = (unsigned short*)(ssrc + 625000);  // 3*16384 bf16 (fragment-major)
  unsigned short* wflo = wfhi + 3 * FEAT * FEAT;            // 3*16384 bf16

  // ---- prep + CSR build (every call: no cross-call state) ----
  prepzero_kernel<<<392, 256, 0, stream>>>(W[0], W[1], W[2], wfhi, wflo, cnt);
  hist_kernel<<<(N_EDGES + 255) / 256, 256, 0, stream>>>(dst, cnt);
  scan_part_kernel<<<NB_SCAN, 256, 0, stream>>>(cnt, part);
  scan_top_kernel<<<1, 256, 0, stream>>>(part, offs);
  scan_down_kernel<<<NB_SCAN, 256, 0, stream>>>(cnt, part, offs);
  fill_kernel<<<(N_EDGES + 255) / 256, 256, 0, stream>>>(src, dst, cnt, ssrc);

  const int gemm_grid = (N_NODES + 63) / 64;       // 782 blocks, 64 rows each
  const int agg_grid  = (N_NODES + 15) / 16;       // 3125 blocks: 4 waves x 4 nodes each
  float* outf = (float*)d_out;

  for (int l = 0; l < 3; ++l) {
    gemm_mfma_kernel<<<gemm_grid, 256, 0, stream>>>(
        (l == 0) ? x : nullptr, (l == 0) ? nullptr : out16,
        wfhi + l * FEAT * FEAT, wflo + l * FEAT * FEAT,
        al[l], ar[l], hH, el, er, l > 0 ? 1 : 0);
    agg_kernel<<<agg_grid, 256, 0, stream>>>(
        hH, el, er, offs, ssrc, b[l], outf, out16, l < 2 ? 1 : 0);
  }
}